// Round 9
// baseline (270.692 us; speedup 1.0000x reference)
//
#include <hip/hip_runtime.h>

#define D 64
#define SGS 72     // sg row stride in shorts (144B): 2-way aliasing only (free)
#define CHUNK 4096 // edges per partition block (merged into setup dispatch)
#define PTH 512    // merged-kernel block threads
#define MAXB 4096  // padded slot per 128-node bucket (mean ~2046, max ~2200 for this input)

typedef __bf16 bf16x8 __attribute__((ext_vector_type(8)));
typedef float f32x4 __attribute__((ext_vector_type(4)));

union U16 { uint4 u; bf16x8 b; };

__device__ __forceinline__ unsigned short f2bf(float f) {
    unsigned u = __float_as_uint(f);
    u += 0x7fff + ((u >> 16) & 1);  // RNE
    return (unsigned short)(u >> 16);
}
__device__ __forceinline__ float bf2f(unsigned short s) {
    return __uint_as_float(((unsigned)s) << 16);
}

// ======= merged setup: cvt(bf16) | pack_b+cvec | padded-bucket partition ======
// (byte-identical to the 201.5 us verified round-6 version)

__global__ __launch_bounds__(PTH) void setup_kernel(const float* __restrict__ in,
                                                    unsigned short* __restrict__ hb0,
                                                    unsigned short* __restrict__ hb1,
                                                    const float* __restrict__ W,
                                                    const float* __restrict__ Wih,
                                                    const float* __restrict__ Whh,
                                                    const float* __restrict__ b,
                                                    unsigned short* __restrict__ Bpack,
                                                    float* __restrict__ cvec,
                                                    const int* __restrict__ src,
                                                    const int* __restrict__ dst,
                                                    int* __restrict__ gcursor,
                                                    unsigned* __restrict__ pairs,
                                                    int n4, int nCvt, int N, int NBUK, int E) {
    __shared__ unsigned pl[CHUNK];          // 16 KB
    __shared__ unsigned short bk[CHUNK];    // 8 KB
    __shared__ int hist[512];
    __shared__ int scn[512];
    __shared__ int goff[512];

    if ((int)blockIdx.x < nCvt) {
        int i = blockIdx.x * PTH + threadIdx.x;
        if (i < n4) {
            float4 v = ((const float4*)in)[i];
            ushort4 o;
            o.x = f2bf(v.x); o.y = f2bf(v.y); o.z = f2bf(v.z); o.w = f2bf(v.w);
            ((ushort4*)hb0)[i] = o;
        }
        if (blockIdx.x == 0 && threadIdx.x < 16) {
            ((ushort4*)(hb0 + (size_t)N * D))[threadIdx.x] = (ushort4){0, 0, 0, 0};
            ((ushort4*)(hb1 + (size_t)N * D))[threadIdx.x] = (ushort4){0, 0, 0, 0};
        }
        return;
    }
    int blk = blockIdx.x - nCvt;
    if (blk < 24) {
        // pack_b branch (24 blocks x 128 active threads)
        if (threadIdx.x >= 128) return;
        int g = blk >> 2, t = blk & 3;
        int ks = threadIdx.x >> 6, lane = threadIdx.x & 63;
        int col = (g % 3) * 64 + t * 16 + (lane & 15);
        int kbase = ks * 32 + ((lane >> 4) & 3) * 8;
        size_t base = ((size_t)(blk * 2 + ks) * 64 + lane) * 8;
#pragma unroll
        for (int j = 0; j < 8; ++j) {
            int k = kbase + j;
            float v;
            if (g < 3) {
                v = 0.f;
#pragma unroll
                for (int m = 0; m < D; ++m) v += Wih[col * D + m] * W[m * D + k];
            } else {
                v = Whh[col * D + k];
            }
            Bpack[base + j] = f2bf(v);
        }
        if (g < 3 && ks == 0 && ((lane >> 4) & 3) == 0) {
            float acc = 0.f;
#pragma unroll
            for (int k = 0; k < D; ++k) acc += Wih[col * D + k] * b[k];
            cvec[col] = acc;
        }
        return;
    }
    // ---- partition branch ----
    {
        int g = blk - 24;
        int t = threadIdx.x;
        int beg = g * CHUNK;
        int end = min(beg + CHUNK, E);
        int m = end - beg;
        hist[t] = 0;
        __syncthreads();
        for (int i = t; i < m; i += PTH)
            atomicAdd(&hist[dst[beg + i] >> 7], 1);
        __syncthreads();
        int own = hist[t];
        scn[t] = own;
        __syncthreads();
        for (int off = 1; off < 512; off <<= 1) {
            int cur = scn[t];
            int add = (t >= off) ? scn[t - off] : 0;
            __syncthreads();
            scn[t] = cur + add;
            __syncthreads();
        }
        int excl = scn[t] - own;
        hist[t] = excl;  // local cursor
        if (t < NBUK) {
            int gbase = own ? atomicAdd(&gcursor[t], own) : 0;
            goff[t] = t * MAXB + gbase - excl;
        }
        __syncthreads();
        for (int i = t; i < m; i += PTH) {
            int d = dst[beg + i];
            int s = src[beg + i];
            int bb = d >> 7;
            int pos = atomicAdd(&hist[bb], 1);
            pl[pos] = ((unsigned)s << 7) | (unsigned)(d & 127);
            bk[pos] = (unsigned short)bb;
        }
        __syncthreads();
        for (int i = t; i < m; i += PTH)
            pairs[goff[bk[i]] + i] = pl[i];
    }
}

// ================= per-node sort within each padded bucket (512 thr) ==========
// (byte-identical to the 201.5 us verified round-6 version)

__global__ __launch_bounds__(512) void bucket_sort_kernel(const unsigned* __restrict__ pairs,
                                                          const int* __restrict__ gcnt,
                                                          int* __restrict__ srcs_sorted,
                                                          int* __restrict__ row_beg,
                                                          int* __restrict__ row_end,
                                                          int NBUK, int N) {
    __shared__ unsigned pl[MAXB];
    __shared__ int srcl[MAXB];
    __shared__ int cnt[128];
    __shared__ int sc[128];
    __shared__ int cur2[128];
    int b = blockIdx.x;
    int t = threadIdx.x;
    int beg = b * MAXB;
    int m = gcnt[b];
    if (m > MAXB) m = MAXB;
    if (t < 128) cnt[t] = 0;
    __syncthreads();
    for (int i = t; i < m; i += 512) {
        unsigned p = pairs[beg + i];
        pl[i] = p;
        atomicAdd(&cnt[p & 127], 1);
    }
    __syncthreads();
    int vt = 0;
    if (t < 128) { vt = cnt[t]; sc[t] = vt; }
    __syncthreads();
    for (int off = 1; off < 128; off <<= 1) {
        int v2 = 0;
        if (t < 128) { v2 = sc[t] + ((t >= off) ? sc[t - off] : 0); }
        __syncthreads();
        if (t < 128) sc[t] = v2;
        __syncthreads();
    }
    int excl = (t < 128) ? (sc[t] - vt) : 0;
    if (t < 128) {
        int gid = b * 128 + t;
        if (gid < N) {
            row_beg[gid] = beg + excl;
            row_end[gid] = beg + excl + vt;
        }
        cur2[t] = excl;
    }
    __syncthreads();
    for (int i = t; i < m; i += 512) {
        unsigned p = pl[i];
        int r = atomicAdd(&cur2[p & 127], 1);
        srcl[r] = (int)(p >> 7);
    }
    __syncthreads();
    for (int i = t; i < m; i += 512) srcs_sorted[beg + i] = srcl[i];
}

// ================= barrier-free fused step ====================================
// 256 threads (4 waves), 64 nodes/block. Each WAVE owns 16 nodes end-to-end:
// gather (8x the verified 2-node pair gather, sg rows wave-private) -> all-6-gate
// MFMA -> in-register GRU epilogue (verified in round 4). No __syncthreads.

template <int G>
__device__ __forceinline__ void rungate(const uint4* __restrict__ bp, int lane,
                                        const bf16x8 (&A)[2], f32x4 (&out)[4]) {
#pragma unroll
    for (int t = 0; t < 4; ++t) out[t] = (f32x4){0.f, 0.f, 0.f, 0.f};
#pragma unroll
    for (int t = 0; t < 4; ++t)
#pragma unroll
        for (int ks = 0; ks < 2; ++ks) {
            U16 u; u.u = bp[((G * 4 + t) * 2 + ks) * 64 + lane];
            out[t] = __builtin_amdgcn_mfma_f32_16x16x32_bf16(A[ks], u.b, out[t], 0, 0, 0);
        }
}

__global__ __launch_bounds__(256) void fused4_kernel(const unsigned short* __restrict__ hb_in,
                                                     unsigned short* __restrict__ hb_out,
                                                     float* __restrict__ Fout, int writeF32,
                                                     const unsigned short* __restrict__ Bpack,
                                                     const float* __restrict__ cvec,
                                                     const float* __restrict__ bih,
                                                     const float* __restrict__ bhh,
                                                     const int* __restrict__ row_beg,
                                                     const int* __restrict__ row_end,
                                                     const int* __restrict__ srcs,
                                                     int N) {
    __shared__ unsigned short sg[64 * SGS];   // 9.2 KB; rows wave-private
    int tid = threadIdx.x;
    int wv = tid >> 6;      // wave 0..3
    int lane = tid & 63;
    int wbase = blockIdx.x * 64 + wv * 16;    // this wave's 16 nodes
    int es = lane >> 3;  // edge slot 0..7
    int fo = lane & 7;   // feature octet 0..7

    // ---- gather: 8 pair-iterations of the verified 2-node gather ----
    for (int p = 0; p < 8; ++p) {
        int nlA = wv * 16 + p, nlB = nlA + 8;
        int nodeA = wbase + p, nodeB = wbase + p + 8;
        int begA = 0, endA = 0, begB = 0, endB = 0;
        if (nodeA < N) { begA = row_beg[nodeA]; endA = row_end[nodeA]; }
        if (nodeB < N) { begB = row_beg[nodeB]; endB = row_end[nodeB]; }

        int sA[4], sB[4];
#pragma unroll
        for (int j = 0; j < 4; ++j) {
            int eA = begA + 8 * j + es;
            int eB = begB + 8 * j + es;
            sA[j] = (eA < endA) ? srcs[eA] : N;
            sB[j] = (eB < endB) ? srcs[eB] : N;
        }
        uint4 dA[4], dB[4];
#pragma unroll
        for (int j = 0; j < 4; ++j) dA[j] = *(const uint4*)(hb_in + (size_t)sA[j] * D + fo * 8);
#pragma unroll
        for (int j = 0; j < 4; ++j) dB[j] = *(const uint4*)(hb_in + (size_t)sB[j] * D + fo * 8);

        float accA[8], accB[8];
#pragma unroll
        for (int j = 0; j < 8; ++j) { accA[j] = 0.f; accB[j] = 0.f; }
#pragma unroll
        for (int j = 0; j < 4; ++j) {
            unsigned ua[4] = {dA[j].x, dA[j].y, dA[j].z, dA[j].w};
            unsigned ub[4] = {dB[j].x, dB[j].y, dB[j].z, dB[j].w};
#pragma unroll
            for (int k = 0; k < 4; ++k) {
                accA[2 * k]     += bf2f((unsigned short)(ua[k] & 0xffff));
                accA[2 * k + 1] += bf2f((unsigned short)(ua[k] >> 16));
                accB[2 * k]     += bf2f((unsigned short)(ub[k] & 0xffff));
                accB[2 * k + 1] += bf2f((unsigned short)(ub[k] >> 16));
            }
        }
        for (int i = begA + 32; i < endA; i += 8) {
            int e = i + es;
            int s = (e < endA) ? srcs[e] : N;
            uint4 dd = *(const uint4*)(hb_in + (size_t)s * D + fo * 8);
            unsigned uu[4] = {dd.x, dd.y, dd.z, dd.w};
#pragma unroll
            for (int k = 0; k < 4; ++k) {
                accA[2 * k]     += bf2f((unsigned short)(uu[k] & 0xffff));
                accA[2 * k + 1] += bf2f((unsigned short)(uu[k] >> 16));
            }
        }
        for (int i = begB + 32; i < endB; i += 8) {
            int e = i + es;
            int s = (e < endB) ? srcs[e] : N;
            uint4 dd = *(const uint4*)(hb_in + (size_t)s * D + fo * 8);
            unsigned uu[4] = {dd.x, dd.y, dd.z, dd.w};
#pragma unroll
            for (int k = 0; k < 4; ++k) {
                accB[2 * k]     += bf2f((unsigned short)(uu[k] & 0xffff));
                accB[2 * k + 1] += bf2f((unsigned short)(uu[k] >> 16));
            }
        }
#pragma unroll
        for (int st = 8; st < 64; st <<= 1)
#pragma unroll
            for (int j = 0; j < 8; ++j) {
                accA[j] += __shfl_xor(accA[j], st, 64);
                accB[j] += __shfl_xor(accB[j], st, 64);
            }
        if (es == 0) {
            uint4 oA, oB;
            oA.x = (unsigned)f2bf(accA[0]) | ((unsigned)f2bf(accA[1]) << 16);
            oA.y = (unsigned)f2bf(accA[2]) | ((unsigned)f2bf(accA[3]) << 16);
            oA.z = (unsigned)f2bf(accA[4]) | ((unsigned)f2bf(accA[5]) << 16);
            oA.w = (unsigned)f2bf(accA[6]) | ((unsigned)f2bf(accA[7]) << 16);
            oB.x = (unsigned)f2bf(accB[0]) | ((unsigned)f2bf(accB[1]) << 16);
            oB.y = (unsigned)f2bf(accB[2]) | ((unsigned)f2bf(accB[3]) << 16);
            oB.z = (unsigned)f2bf(accB[4]) | ((unsigned)f2bf(accB[5]) << 16);
            oB.w = (unsigned)f2bf(accB[6]) | ((unsigned)f2bf(accB[7]) << 16);
            *(uint4*)(sg + nlA * SGS + fo * 8) = oA;
            *(uint4*)(sg + nlB * SGS + fo * 8) = oB;
        }
    }
    // no __syncthreads: sg rows are written and read by the same wave only

    // ---- MFMA + in-register GRU epilogue for this wave's 16 nodes ----
    {
        int r16 = lane & 15, quad = lane >> 4;
        const uint4* bp = (const uint4*)Bpack;

        bf16x8 aM[2], aH[2];
#pragma unroll
        for (int ks = 0; ks < 2; ++ks) {
            U16 u; u.u = *(const uint4*)(sg + (wv * 16 + r16) * SGS + ks * 32 + quad * 8);
            aM[ks] = u.b;
        }
        int hrow = wbase + r16;
        if (hrow >= N) hrow = N - 1;
#pragma unroll
        for (int ks = 0; ks < 2; ++ks) {
            U16 u; u.u = *(const uint4*)(hb_in + (size_t)hrow * D + ks * 32 + quad * 8);
            aH[ks] = u.b;
        }

        float degv[4];
#pragma unroll
        for (int r = 0; r < 4; ++r) {
            int node = wbase + quad * 4 + r;
            degv[r] = (node < N) ? (float)(row_end[node] - row_beg[node]) : 0.f;
        }

        f32x4 t0[4], t1[4];

        // r-gate: hr (g3) + ir (g0)
        rungate<3>(bp, lane, aH, t0);
        rungate<0>(bp, lane, aM, t1);
        f32x4 rr[4];
#pragma unroll
        for (int t = 0; t < 4; ++t) {
            int f = t * 16 + r16;
            float bi = bih[f], bh = bhh[f], cv = cvec[f];
#pragma unroll
            for (int r = 0; r < 4; ++r) {
                float x = t1[t][r] + bi + degv[r] * cv + t0[t][r] + bh;
                rr[t][r] = 1.f / (1.f + __expf(-x));
            }
        }
        // z-gate: hz (g4) + iz (g1)
        rungate<4>(bp, lane, aH, t0);
        rungate<1>(bp, lane, aM, t1);
        f32x4 zz[4];
#pragma unroll
        for (int t = 0; t < 4; ++t) {
            int f = t * 16 + r16;
            float bi = bih[64 + f], bh = bhh[64 + f], cv = cvec[64 + f];
#pragma unroll
            for (int r = 0; r < 4; ++r) {
                float x = t1[t][r] + bi + degv[r] * cv + t0[t][r] + bh;
                zz[t][r] = 1.f / (1.f + __expf(-x));
            }
        }
        // n-gate: hn (g5) + in (g2), then combine
        rungate<5>(bp, lane, aH, t0);
        rungate<2>(bp, lane, aM, t1);
#pragma unroll
        for (int t = 0; t < 4; ++t) {
            int f = t * 16 + r16;
            float bi = bih[128 + f], bh = bhh[128 + f], cv = cvec[128 + f];
#pragma unroll
            for (int r = 0; r < 4; ++r) {
                int node = wbase + quad * 4 + r;
                if (node < N) {
                    float hv = bf2f(hb_in[(size_t)node * D + f]);
                    float nn = tanhf(t1[t][r] + bi + degv[r] * cv + rr[t][r] * (t0[t][r] + bh));
                    float z = zz[t][r];
                    float hnew = (1.f - z) * nn + z * hv;
                    if (writeF32) Fout[(size_t)node * D + f] = hnew;
                    else hb_out[(size_t)node * D + f] = f2bf(hnew);
                }
            }
        }
    }
}

extern "C" void kernel_launch(void* const* d_in, const int* in_sizes, int n_in,
                              void* d_out, int out_size, void* d_ws, size_t ws_size,
                              hipStream_t stream) {
    const float* node_in = (const float*)d_in[0];
    const float* W       = (const float*)d_in[1];
    const float* b       = (const float*)d_in[2];
    const float* Wih     = (const float*)d_in[3];
    const float* Whh     = (const float*)d_in[4];
    const float* bih     = (const float*)d_in[5];
    const float* bhh     = (const float*)d_in[6];
    const int*   src     = (const int*)d_in[7];
    const int*   dst     = (const int*)d_in[8];
    const int N = in_sizes[0] / D;
    const int E = in_sizes[7];
    float* out = (float*)d_out;

    const int G = (E + CHUNK - 1) / CHUNK;          // 196
    const int NBUK = (N + 127) >> 7;                // 391 (must be <= 512)

    char* ws = (char*)d_ws;
    size_t off = 0;
    auto alloc = [&](size_t bytes) -> void* {
        void* p = ws + off;
        off += (bytes + 255) & ~(size_t)255;
        return p;
    };
    unsigned short* hb0    = (unsigned short*)alloc((size_t)(N + 1) * D * 2);  // +1: zero sentinel
    unsigned short* hb1    = (unsigned short*)alloc((size_t)(N + 1) * D * 2);
    int*   row_beg         = (int*)alloc((size_t)NBUK * 128 * sizeof(int));
    int*   row_end         = (int*)alloc((size_t)NBUK * 128 * sizeof(int));
    int*   srcs_sorted     = (int*)alloc((size_t)NBUK * MAXB * sizeof(int));
    unsigned* pairs        = (unsigned*)alloc((size_t)NBUK * MAXB * sizeof(unsigned));
    int*   gcursor         = (int*)alloc((size_t)NBUK * sizeof(int));
    unsigned short* Bpack  = (unsigned short*)alloc((size_t)6 * 4 * 2 * 64 * 8 * 2);
    float* cvec            = (float*)alloc((size_t)192 * sizeof(float));

    // zero bucket cursors (partition's only dependency) without a kernel
    hipMemsetAsync(gcursor, 0, (size_t)NBUK * sizeof(int), stream);

    // merged dispatch: cvt | pack_b | partition co-run (partition independent)
    const int n4 = N * D / 4;
    const int nCvt = (n4 + PTH - 1) / PTH;
    setup_kernel<<<nCvt + 24 + G, PTH, 0, stream>>>(node_in, hb0, hb1, W, Wih, Whh, b,
                                                    Bpack, cvec, src, dst, gcursor, pairs,
                                                    n4, nCvt, N, NBUK, E);

    // per-bucket per-node sort -> padded CSR
    bucket_sort_kernel<<<NBUK, 512, 0, stream>>>(pairs, gcursor, srcs_sorted,
                                                 row_beg, row_end, NBUK, N);

    // 3 barrier-free fused steps, ping-pong bf16 h; f32 out on the last step only
    const int grid = (N + 63) / 64;
    fused4_kernel<<<grid, 256, 0, stream>>>(hb0, hb1, out, 0, Bpack, cvec, bih, bhh,
                                            row_beg, row_end, srcs_sorted, N);
    fused4_kernel<<<grid, 256, 0, stream>>>(hb1, hb0, out, 0, Bpack, cvec, bih, bhh,
                                            row_beg, row_end, srcs_sorted, N);
    fused4_kernel<<<grid, 256, 0, stream>>>(hb0, hb1, out, 1, Bpack, cvec, bih, bhh,
                                            row_beg, row_end, srcs_sorted, N);
}

// Round 10
// 200.665 us; speedup vs baseline: 1.3490x; 1.3490x over previous
//
#include <hip/hip_runtime.h>

#define D 64
#define EXS 388    // ex row stride in floats: 388%32=4 -> only 2-way bank aliasing (free)
#define SGS 72     // sg row stride in shorts (144B): 2-way aliasing only (free)
#define CHUNK 4096 // edges per partition block (merged into setup dispatch)
#define PTH 512    // merged-kernel block threads
#define MAXB 4096  // padded slot per 128-node bucket (mean ~2046, max ~2200 for this input)

typedef __bf16 bf16x8 __attribute__((ext_vector_type(8)));
typedef float f32x4 __attribute__((ext_vector_type(4)));

union U16 { uint4 u; bf16x8 b; };

__device__ __forceinline__ unsigned short f2bf(float f) {
    unsigned u = __float_as_uint(f);
    u += 0x7fff + ((u >> 16) & 1);  // RNE
    return (unsigned short)(u >> 16);
}
__device__ __forceinline__ float bf2f(unsigned short s) {
    return __uint_as_float(((unsigned)s) << 16);
}

// ======= merged setup: cvt(bf16) | pack_b+cvec | padded-bucket partition ======
// Identical to the 201.5 us round-6 version EXCEPT the 512-entry exclusive scan:
// 18-barrier LDS ladder -> barrier-free wave shfl_up scan + 1-barrier combine.

__global__ __launch_bounds__(PTH) void setup_kernel(const float* __restrict__ in,
                                                    unsigned short* __restrict__ hb0,
                                                    unsigned short* __restrict__ hb1,
                                                    const float* __restrict__ W,
                                                    const float* __restrict__ Wih,
                                                    const float* __restrict__ Whh,
                                                    const float* __restrict__ b,
                                                    unsigned short* __restrict__ Bpack,
                                                    float* __restrict__ cvec,
                                                    const int* __restrict__ src,
                                                    const int* __restrict__ dst,
                                                    int* __restrict__ gcursor,
                                                    unsigned* __restrict__ pairs,
                                                    int n4, int nCvt, int N, int NBUK, int E) {
    __shared__ unsigned pl[CHUNK];          // 16 KB
    __shared__ unsigned short bk[CHUNK];    // 8 KB
    __shared__ int hist[512];
    __shared__ int wpart[8];
    __shared__ int goff[512];

    if ((int)blockIdx.x < nCvt) {
        int i = blockIdx.x * PTH + threadIdx.x;
        if (i < n4) {
            float4 v = ((const float4*)in)[i];
            ushort4 o;
            o.x = f2bf(v.x); o.y = f2bf(v.y); o.z = f2bf(v.z); o.w = f2bf(v.w);
            ((ushort4*)hb0)[i] = o;
        }
        if (blockIdx.x == 0 && threadIdx.x < 16) {
            ((ushort4*)(hb0 + (size_t)N * D))[threadIdx.x] = (ushort4){0, 0, 0, 0};
            ((ushort4*)(hb1 + (size_t)N * D))[threadIdx.x] = (ushort4){0, 0, 0, 0};
        }
        return;
    }
    int blk = blockIdx.x - nCvt;
    if (blk < 24) {
        // pack_b branch (24 blocks x 128 active threads)
        if (threadIdx.x >= 128) return;
        int g = blk >> 2, t = blk & 3;
        int ks = threadIdx.x >> 6, lane = threadIdx.x & 63;
        int col = (g % 3) * 64 + t * 16 + (lane & 15);
        int kbase = ks * 32 + ((lane >> 4) & 3) * 8;
        size_t base = ((size_t)(blk * 2 + ks) * 64 + lane) * 8;
#pragma unroll
        for (int j = 0; j < 8; ++j) {
            int k = kbase + j;
            float v;
            if (g < 3) {
                v = 0.f;
#pragma unroll
                for (int m = 0; m < D; ++m) v += Wih[col * D + m] * W[m * D + k];
            } else {
                v = Whh[col * D + k];
            }
            Bpack[base + j] = f2bf(v);
        }
        if (g < 3 && ks == 0 && ((lane >> 4) & 3) == 0) {
            float acc = 0.f;
#pragma unroll
            for (int k = 0; k < D; ++k) acc += Wih[col * D + k] * b[k];
            cvec[col] = acc;
        }
        return;
    }
    // ---- partition branch ----
    {
        int g = blk - 24;
        int t = threadIdx.x;
        int beg = g * CHUNK;
        int end = min(beg + CHUNK, E);
        int m = end - beg;
        hist[t] = 0;
        __syncthreads();
        for (int i = t; i < m; i += PTH)
            atomicAdd(&hist[dst[beg + i] >> 7], 1);
        __syncthreads();
        int own = hist[t];
        // wave shfl_up inclusive scan (no barriers) + cross-wave combine (1 barrier)
        int lane6 = t & 63, wv6 = t >> 6;
        int v = own;
#pragma unroll
        for (int off = 1; off < 64; off <<= 1) {
            int nv = __shfl_up(v, off, 64);
            if (lane6 >= off) v += nv;
        }
        if (lane6 == 63) wpart[wv6] = v;
        __syncthreads();
        int basep = 0;
#pragma unroll
        for (int i = 0; i < 8; ++i) basep += (i < wv6) ? wpart[i] : 0;
        int excl = v + basep - own;
        hist[t] = excl;  // local cursor
        if (t < NBUK) {
            int gbase = own ? atomicAdd(&gcursor[t], own) : 0;
            goff[t] = t * MAXB + gbase - excl;
        }
        __syncthreads();
        for (int i = t; i < m; i += PTH) {
            int d = dst[beg + i];
            int s = src[beg + i];
            int bb = d >> 7;
            int pos = atomicAdd(&hist[bb], 1);
            pl[pos] = ((unsigned)s << 7) | (unsigned)(d & 127);
            bk[pos] = (unsigned short)bb;
        }
        __syncthreads();
        for (int i = t; i < m; i += PTH)
            pairs[goff[bk[i]] + i] = pl[i];
    }
}

// ================= per-node sort within each padded bucket (512 thr) ==========
// Identical to round-6 EXCEPT the 128-entry scan: ladder -> wave shfl_up scan.

__global__ __launch_bounds__(512) void bucket_sort_kernel(const unsigned* __restrict__ pairs,
                                                          const int* __restrict__ gcnt,
                                                          int* __restrict__ srcs_sorted,
                                                          int* __restrict__ row_beg,
                                                          int* __restrict__ row_end,
                                                          int NBUK, int N) {
    __shared__ unsigned pl[MAXB];
    __shared__ int srcl[MAXB];
    __shared__ int cnt[128];
    __shared__ int wpart[2];
    __shared__ int cur2[128];
    int b = blockIdx.x;
    int t = threadIdx.x;
    int beg = b * MAXB;
    int m = gcnt[b];
    if (m > MAXB) m = MAXB;
    if (t < 128) cnt[t] = 0;
    __syncthreads();
    for (int i = t; i < m; i += 512) {
        unsigned p = pairs[beg + i];
        pl[i] = p;
        atomicAdd(&cnt[p & 127], 1);
    }
    __syncthreads();
    int vt = (t < 128) ? cnt[t] : 0;
    // wave shfl_up scan over the 128 entries held by waves 0-1
    int lane6 = t & 63, wv6 = t >> 6;
    int v = vt;
#pragma unroll
    for (int off = 1; off < 64; off <<= 1) {
        int nv = __shfl_up(v, off, 64);
        if (lane6 >= off) v += nv;
    }
    if (t < 128 && lane6 == 63) wpart[wv6] = v;
    __syncthreads();
    if (t < 128) {
        int basep = (wv6 == 1) ? wpart[0] : 0;
        int excl = v + basep - vt;
        int gid = b * 128 + t;
        if (gid < N) {
            row_beg[gid] = beg + excl;
            row_end[gid] = beg + excl + vt;
        }
        cur2[t] = excl;
    }
    __syncthreads();
    for (int i = t; i < m; i += 512) {
        unsigned p = pl[i];
        int r = atomicAdd(&cur2[p & 127], 1);
        srcl[r] = (int)(p >> 7);
    }
    __syncthreads();
    for (int i = t; i < m; i += 512) srcs_sorted[beg + i] = srcl[i];
}

// ================= fused step: parallel gather + GRU(MFMA) ====================
// (byte-identical to the 201.5 us verified round-6 version)

__global__ __launch_bounds__(512) void fused2_kernel(const unsigned short* __restrict__ hb_in,
                                                     unsigned short* __restrict__ hb_out,
                                                     float* __restrict__ Fout, int writeF32,
                                                     const unsigned short* __restrict__ Bpack,
                                                     const float* __restrict__ cvec,
                                                     const float* __restrict__ bih,
                                                     const float* __restrict__ bhh,
                                                     const int* __restrict__ row_beg,
                                                     const int* __restrict__ row_end,
                                                     const int* __restrict__ srcs,
                                                     int N) {
    __shared__ unsigned short sg[16 * SGS];
    __shared__ float ex[16 * EXS];
    int tid = threadIdx.x;
    int g = tid >> 6;       // wave 0..7
    int lane = tid & 63;
    int base = blockIdx.x * 16;

    // ---- gather phase: 2 nodes per wave, one parallel round ----
    {
        int es = lane >> 3;  // edge slot 0..7
        int fo = lane & 7;   // feature octet 0..7
        int nlA = g, nlB = g + 8;
        int nodeA = base + nlA, nodeB = base + nlB;
        int begA = 0, endA = 0, begB = 0, endB = 0;
        if (nodeA < N) { begA = row_beg[nodeA]; endA = row_end[nodeA]; }
        if (nodeB < N) { begB = row_beg[nodeB]; endB = row_end[nodeB]; }

        int sA[4], sB[4];
#pragma unroll
        for (int j = 0; j < 4; ++j) {
            int eA = begA + 8 * j + es;
            int eB = begB + 8 * j + es;
            sA[j] = (eA < endA) ? srcs[eA] : N;
            sB[j] = (eB < endB) ? srcs[eB] : N;
        }
        uint4 dA[4], dB[4];
#pragma unroll
        for (int j = 0; j < 4; ++j) dA[j] = *(const uint4*)(hb_in + (size_t)sA[j] * D + fo * 8);
#pragma unroll
        for (int j = 0; j < 4; ++j) dB[j] = *(const uint4*)(hb_in + (size_t)sB[j] * D + fo * 8);

        float accA[8], accB[8];
#pragma unroll
        for (int j = 0; j < 8; ++j) { accA[j] = 0.f; accB[j] = 0.f; }
#pragma unroll
        for (int j = 0; j < 4; ++j) {
            unsigned ua[4] = {dA[j].x, dA[j].y, dA[j].z, dA[j].w};
            unsigned ub[4] = {dB[j].x, dB[j].y, dB[j].z, dB[j].w};
#pragma unroll
            for (int k = 0; k < 4; ++k) {
                accA[2 * k]     += bf2f((unsigned short)(ua[k] & 0xffff));
                accA[2 * k + 1] += bf2f((unsigned short)(ua[k] >> 16));
                accB[2 * k]     += bf2f((unsigned short)(ub[k] & 0xffff));
                accB[2 * k + 1] += bf2f((unsigned short)(ub[k] >> 16));
            }
        }
        for (int i = begA + 32; i < endA; i += 8) {
            int e = i + es;
            int s = (e < endA) ? srcs[e] : N;
            uint4 dd = *(const uint4*)(hb_in + (size_t)s * D + fo * 8);
            unsigned uu[4] = {dd.x, dd.y, dd.z, dd.w};
#pragma unroll
            for (int k = 0; k < 4; ++k) {
                accA[2 * k]     += bf2f((unsigned short)(uu[k] & 0xffff));
                accA[2 * k + 1] += bf2f((unsigned short)(uu[k] >> 16));
            }
        }
        for (int i = begB + 32; i < endB; i += 8) {
            int e = i + es;
            int s = (e < endB) ? srcs[e] : N;
            uint4 dd = *(const uint4*)(hb_in + (size_t)s * D + fo * 8);
            unsigned uu[4] = {dd.x, dd.y, dd.z, dd.w};
#pragma unroll
            for (int k = 0; k < 4; ++k) {
                accB[2 * k]     += bf2f((unsigned short)(uu[k] & 0xffff));
                accB[2 * k + 1] += bf2f((unsigned short)(uu[k] >> 16));
            }
        }
#pragma unroll
        for (int st = 8; st < 64; st <<= 1)
#pragma unroll
            for (int j = 0; j < 8; ++j) {
                accA[j] += __shfl_xor(accA[j], st, 64);
                accB[j] += __shfl_xor(accB[j], st, 64);
            }
        if (es == 0) {
            uint4 oA, oB;
            oA.x = (unsigned)f2bf(accA[0]) | ((unsigned)f2bf(accA[1]) << 16);
            oA.y = (unsigned)f2bf(accA[2]) | ((unsigned)f2bf(accA[3]) << 16);
            oA.z = (unsigned)f2bf(accA[4]) | ((unsigned)f2bf(accA[5]) << 16);
            oA.w = (unsigned)f2bf(accA[6]) | ((unsigned)f2bf(accA[7]) << 16);
            oB.x = (unsigned)f2bf(accB[0]) | ((unsigned)f2bf(accB[1]) << 16);
            oB.y = (unsigned)f2bf(accB[2]) | ((unsigned)f2bf(accB[3]) << 16);
            oB.z = (unsigned)f2bf(accB[4]) | ((unsigned)f2bf(accB[5]) << 16);
            oB.w = (unsigned)f2bf(accB[6]) | ((unsigned)f2bf(accB[7]) << 16);
            *(uint4*)(sg + nlA * SGS + fo * 8) = oA;
            *(uint4*)(sg + nlB * SGS + fo * 8) = oB;
        }
    }
    __syncthreads();

    // ---- MFMA phase: waves 0-5 compute the 6 gate-matrices ----
    if (g < 6) {
        int r16 = lane & 15, quad = lane >> 4;
        bf16x8 bf[4][2];
        const uint4* bp = (const uint4*)Bpack;
#pragma unroll
        for (int t = 0; t < 4; ++t)
#pragma unroll
            for (int ks = 0; ks < 2; ++ks) {
                U16 u; u.u = bp[((g * 4 + t) * 2 + ks) * 64 + lane];
                bf[t][ks] = u.b;
            }
        bf16x8 af[2];
        if (g < 3) {
#pragma unroll
            for (int ks = 0; ks < 2; ++ks) {
                U16 u; u.u = *(const uint4*)(sg + r16 * SGS + ks * 32 + quad * 8);
                af[ks] = u.b;
            }
        } else {
            int row = base + r16;
            if (row >= N) row = N - 1;
#pragma unroll
            for (int ks = 0; ks < 2; ++ks) {
                U16 u; u.u = *(const uint4*)(hb_in + (size_t)row * D + ks * 32 + quad * 8);
                af[ks] = u.b;
            }
        }
        f32x4 acc[4];
#pragma unroll
        for (int t = 0; t < 4; ++t) acc[t] = (f32x4){0.f, 0.f, 0.f, 0.f};
#pragma unroll
        for (int t = 0; t < 4; ++t)
#pragma unroll
            for (int ks = 0; ks < 2; ++ks)
                acc[t] = __builtin_amdgcn_mfma_f32_16x16x32_bf16(af[ks], bf[t][ks], acc[t], 0, 0, 0);
#pragma unroll
        for (int t = 0; t < 4; ++t)
#pragma unroll
            for (int r = 0; r < 4; ++r)
                ex[(quad * 4 + r) * EXS + g * 64 + t * 16 + r16] = acc[t][r];
    }
    __syncthreads();

    // ---- elementwise epilogue: all 8 waves over 16x64 elements ----
    for (int idx = tid; idx < 16 * D; idx += 512) {
        int i = idx >> 6, d = idx & 63;
        int node = base + i;
        if (node < N) {
            const float* p = &ex[i * EXS];
            float deg = (float)(row_end[node] - row_beg[node]);
            float ir = p[d] + bih[d] + deg * cvec[d];
            float iz = p[64 + d] + bih[64 + d] + deg * cvec[64 + d];
            float in_ = p[128 + d] + bih[128 + d] + deg * cvec[128 + d];
            float hr = p[192 + d] + bhh[d];
            float hz = p[256 + d] + bhh[64 + d];
            float hn = p[320 + d] + bhh[128 + d];
            float h = bf2f(hb_in[(size_t)node * D + d]);
            float r = 1.f / (1.f + __expf(-(ir + hr)));
            float z = 1.f / (1.f + __expf(-(iz + hz)));
            float nn = tanhf(in_ + r * hn);
            float hnew = (1.f - z) * nn + z * h;
            if (writeF32) Fout[(size_t)node * D + d] = hnew;       // final step: f32 only
            else hb_out[(size_t)node * D + d] = f2bf(hnew);        // else: carry bf16
        }
    }
}

extern "C" void kernel_launch(void* const* d_in, const int* in_sizes, int n_in,
                              void* d_out, int out_size, void* d_ws, size_t ws_size,
                              hipStream_t stream) {
    const float* node_in = (const float*)d_in[0];
    const float* W       = (const float*)d_in[1];
    const float* b       = (const float*)d_in[2];
    const float* Wih     = (const float*)d_in[3];
    const float* Whh     = (const float*)d_in[4];
    const float* bih     = (const float*)d_in[5];
    const float* bhh     = (const float*)d_in[6];
    const int*   src     = (const int*)d_in[7];
    const int*   dst     = (const int*)d_in[8];
    const int N = in_sizes[0] / D;
    const int E = in_sizes[7];
    float* out = (float*)d_out;

    const int G = (E + CHUNK - 1) / CHUNK;          // 196
    const int NBUK = (N + 127) >> 7;                // 391 (must be <= 512)

    char* ws = (char*)d_ws;
    size_t off = 0;
    auto alloc = [&](size_t bytes) -> void* {
        void* p = ws + off;
        off += (bytes + 255) & ~(size_t)255;
        return p;
    };
    unsigned short* hb0    = (unsigned short*)alloc((size_t)(N + 1) * D * 2);  // +1: zero sentinel
    unsigned short* hb1    = (unsigned short*)alloc((size_t)(N + 1) * D * 2);
    int*   row_beg         = (int*)alloc((size_t)NBUK * 128 * sizeof(int));
    int*   row_end         = (int*)alloc((size_t)NBUK * 128 * sizeof(int));
    int*   srcs_sorted     = (int*)alloc((size_t)NBUK * MAXB * sizeof(int));
    unsigned* pairs        = (unsigned*)alloc((size_t)NBUK * MAXB * sizeof(unsigned));
    int*   gcursor         = (int*)alloc((size_t)NBUK * sizeof(int));
    unsigned short* Bpack  = (unsigned short*)alloc((size_t)6 * 4 * 2 * 64 * 8 * 2);
    float* cvec            = (float*)alloc((size_t)192 * sizeof(float));

    // zero bucket cursors (partition's only dependency) without a kernel
    hipMemsetAsync(gcursor, 0, (size_t)NBUK * sizeof(int), stream);

    // merged dispatch: cvt | pack_b | partition co-run (partition independent)
    const int n4 = N * D / 4;
    const int nCvt = (n4 + PTH - 1) / PTH;
    setup_kernel<<<nCvt + 24 + G, PTH, 0, stream>>>(node_in, hb0, hb1, W, Wih, Whh, b,
                                                    Bpack, cvec, src, dst, gcursor, pairs,
                                                    n4, nCvt, N, NBUK, E);

    // per-bucket per-node sort -> padded CSR
    bucket_sort_kernel<<<NBUK, 512, 0, stream>>>(pairs, gcursor, srcs_sorted,
                                                 row_beg, row_end, NBUK, N);

    // 3 fused steps, ping-pong bf16 h; f32 out on the last step only
    const int grid = (N + 15) / 16;
    fused2_kernel<<<grid, 512, 0, stream>>>(hb0, hb1, out, 0, Bpack, cvec, bih, bhh,
                                            row_beg, row_end, srcs_sorted, N);
    fused2_kernel<<<grid, 512, 0, stream>>>(hb1, hb0, out, 0, Bpack, cvec, bih, bhh,
                                            row_beg, row_end, srcs_sorted, N);
    fused2_kernel<<<grid, 512, 0, stream>>>(hb0, hb1, out, 1, Bpack, cvec, bih, bhh,
                                            row_beg, row_end, srcs_sorted, N);
}